// Round 13
// baseline (166.002 us; speedup 1.0000x reference)
//
#include <hip/hip_runtime.h>
#include <hip/hip_bf16.h>
#include <math.h>

// Sizes fixed by the reference
#define NN 512
#define NQ 448
#define ND 64          // num_denoising
#define NC 91
#define ED 256
#define NH 8
#define NBLK 512

typedef __attribute__((ext_vector_type(8))) short bf16x8;
typedef __attribute__((ext_vector_type(4))) float f32x4;

struct FreqArg { float fr[32]; };

// Device-global scratch (every cell rewritten each launch before read)
__device__ int   g_perm[NN];
__device__ float g_c0[NH];
__device__ float g_afull[NN * NH];
__device__ float g_part[64 * 512];  // fold partials [(h*8+cc)*512 + d'] (d'<256: pos, >=256: rank)
__device__ float g_scores[NQ];
__device__ float g_nr[NQ * ED];     // normal_rank = rank_emb @ pre_W^T + pre_b
__device__ __align__(16) unsigned short g_WB[8 * 64 * 8];  // bf16 A-frags [step][lane][elem]
// Tree-barrier state. Invariant: ALL zero at kernel entry and exit (graph-replay safe).
__device__ unsigned g_grp[2][64];
__device__ unsigned g_root[2];
__device__ unsigned g_flag[2];
__device__ unsigned g_exit;

__device__ inline unsigned short f2bfbits(float x) {
    __hip_bfloat16 h = __float2bfloat16(x);
    union { __hip_bfloat16 b; unsigned short u; } cv; cv.b = h; return cv.u;
}

// Two-level grid barrier. Safe: all 512 blocks co-resident (2 blocks/CU: LDS 49.3KB<80KB,
// VGPR<=128 via launch_bounds). Group counters and root self-reset; flag reset at kernel exit.
__device__ inline void grid_barrier(int id) {
    __syncthreads();
    if (threadIdx.x == 0) {
        __threadfence();
        int grp = blockIdx.x >> 3;   // 64 groups x 8 blocks
        unsigned ga = __hip_atomic_fetch_add(&g_grp[id][grp], 1u, __ATOMIC_ACQ_REL, __HIP_MEMORY_SCOPE_AGENT);
        if (ga == 7u) {
            __hip_atomic_store(&g_grp[id][grp], 0u, __ATOMIC_RELAXED, __HIP_MEMORY_SCOPE_AGENT);
            unsigned gr = __hip_atomic_fetch_add(&g_root[id], 1u, __ATOMIC_ACQ_REL, __HIP_MEMORY_SCOPE_AGENT);
            if (gr == 63u) {
                __hip_atomic_store(&g_root[id], 0u, __ATOMIC_RELAXED, __HIP_MEMORY_SCOPE_AGENT);
                __hip_atomic_store(&g_flag[id], 1u, __ATOMIC_RELEASE, __HIP_MEMORY_SCOPE_AGENT);
            }
        }
        while (__hip_atomic_load(&g_flag[id], __ATOMIC_ACQUIRE, __HIP_MEMORY_SCOPE_AGENT) == 0u)
            __builtin_amdgcn_s_sleep(1);
        __threadfence();
    }
    __syncthreads();
}

// ---------- phase-1 tasks: 0..223 nr tiles; 224..287 fold partials; 288..295 scores; 296 c0
__device__ void task_p1(int tk, int t, float* smem,
                        const float* __restrict__ logits, const float* __restrict__ attn_W,
                        const float* __restrict__ attn_b, const float* __restrict__ post_W,
                        const float* __restrict__ post_b, const float* __restrict__ pre_W,
                        const float* __restrict__ pre_b, const float* __restrict__ rank_emb) {
    if (tk < 224) {
        int q0 = (tk >> 3) * 16, d0 = (tk & 7) * 32;
        float* sP = smem;               // [32][257]
        float* sR = smem + 32 * 257;    // [16][257]
        for (int v = t; v < 32 * 256; v += 512)
            sP[(v >> 8) * 257 + (v & 255)] = pre_W[(size_t)(d0 + (v >> 8)) * ED + (v & 255)];
        for (int v = t; v < 16 * 256; v += 512)
            sR[(v >> 8) * 257 + (v & 255)] = rank_emb[(size_t)(q0 + (v >> 8)) * ED + (v & 255)];
        __syncthreads();
        int q = t >> 5, dl = t & 31;
        float acc = pre_b[d0 + dl];
#pragma unroll 8
        for (int e = 0; e < 256; ++e) acc = fmaf(sR[q * 257 + e], sP[dl * 257 + e], acc);
        g_nr[(size_t)(q0 + q) * ED + d0 + dl] = acc;
    } else if (tk < 288) {
        int f = tk - 224;
        int h = f >> 3, cc = f & 7;
        float* sAW = smem;
        if (t < 32) sAW[t] = attn_W[h * ED + cc * 32 + t];
        __syncthreads();
        float m = 0.f;
        const float* pw = post_W + (size_t)(cc * 32) * 512 + t;
#pragma unroll
        for (int ci = 0; ci < 32; ++ci) m = fmaf(sAW[ci], pw[(size_t)ci * 512], m);
        g_part[(size_t)f * 512 + t] = m;
    } else if (tk < 296) {
        int W = (tk - 288) * 8 + (t >> 6);
        int lane = t & 63;
        for (int qi = 0; qi < 7; ++qi) {
            int q = W * 7 + qi;
            const float* row = logits + (size_t)(ND + q) * NC;
            float m = (lane < NC) ? row[lane] : -INFINITY;
            int c2 = lane + 64;
            if (c2 < NC) m = fmaxf(m, row[c2]);
            for (int off = 32; off > 0; off >>= 1) m = fmaxf(m, __shfl_down(m, off, 64));
            if (lane == 0) g_scores[q] = m;   // sigmoid(max)==max(sigmoid): rank raw logits
        }
    } else {
        int h = t >> 6, lane = t & 63;
        float v = 0.f;
#pragma unroll
        for (int k = 0; k < 4; ++k) {
            int c = lane + 64 * k;
            v = fmaf(attn_W[h * ED + c], post_b[c], v);
        }
        for (int off = 32; off > 0; off >>= 1) v += __shfl_down(v, off, 64);
        if (lane == 0) g_c0[h] = attn_b[h] + v;
    }
}

// ---------- phase-2 tasks: 0..55 afull tiles (8 q); 56..57 WB pack; 58 argsort
__device__ void task_p2(int bid, int t, float* smem, float* __restrict__ out2) {
    if (bid < 56) {
        float* sW = smem;             // [8][260] w2a (redundant per-block reduce)
        float* sN = smem + 8 * 260;   // [8][260] nr rows of this q-tile
        int q0 = bid * 8;
        for (int v = t; v < 2048; v += 512) {
            int h = v >> 8, d = v & 255;
            float s = 0.f;
#pragma unroll
            for (int cc = 0; cc < 8; ++cc) s += g_part[(size_t)(h * 8 + cc) * 512 + 256 + d];
            sW[h * 260 + d] = s;
        }
        for (int v = t; v < 2048; v += 512)
            sN[(v >> 8) * 260 + (v & 255)] = g_nr[(size_t)(q0 + (v >> 8)) * ED + (v & 255)];
        __syncthreads();
        int o = t >> 3, sub = t & 7;       // 64 outputs (8q x 8h), 8 threads each
        int q = o >> 3, h = o & 7;
        float a = 0.f;
#pragma unroll 8
        for (int e2 = 0; e2 < 32; ++e2) {
            int e = sub + 8 * e2;
            a = fmaf(sN[q * 260 + e], sW[h * 260 + e], a);
        }
        a += __shfl_xor(a, 1, 64);
        a += __shfl_xor(a, 2, 64);
        a += __shfl_xor(a, 4, 64);
        if (sub == 0) g_afull[(size_t)(ND + q0 + q) * NH + h] = a;
    } else if (bid < 58) {
        for (int vv = t; vv < 2048; vv += 512) {
            int v = (bid - 56) * 2048 + vv;
            int s = v >> 9;
            int lane = (v >> 3) & 63;
            int ii = v & 7;
            int g = lane >> 4, hh = lane & 15;
            int k = s * 4 + (ii >> 1), r = ii & 1;
            int d = g * 64 + 2 * k + r;
            float w = 0.f;
            if (hh < NH) {
#pragma unroll
                for (int cc = 0; cc < 8; ++cc) w += g_part[(size_t)(hh * 8 + cc) * 512 + d];
            }
            g_WB[v] = f2bfbits(w);
        }
    } else if (bid == 58) {
        float* sc = smem;
        for (int v = t; v < NQ; v += 512) sc[v] = g_scores[v];
        __syncthreads();
        if (t < NQ) {
            float s1 = sc[t];
            int r1 = 0;
            for (int j = 0; j < NQ; ++j) {
                float sj = sc[j];
                r1 += ((sj > s1) || (sj == s1 && j < t)) ? 1 : 0;
            }
            g_perm[ND + r1] = ND + t;
            out2[ND + r1] = (float)(ND + t);
        }
        if (t < ND) {
            g_perm[t] = t;
            out2[t] = (float)t;
            for (int h = 0; h < NH; ++h) g_afull[t * NH + h] = 0.f;
        }
    }
}

// ---------- fused kernel: 512 blocks x 512 threads, 2 blocks/CU co-resident
__global__ __launch_bounds__(512, 4) void fused_all(const float* __restrict__ boxes,
                                                    const float* __restrict__ logits,
                                                    const float* __restrict__ rank_emb,
                                                    const float* __restrict__ pre_W,
                                                    const float* __restrict__ pre_b,
                                                    const float* __restrict__ post_W,
                                                    const float* __restrict__ post_b,
                                                    const float* __restrict__ attn_W,
                                                    const float* __restrict__ attn_b,
                                                    FreqArg fa,
                                                    float* __restrict__ out) {
    __shared__ __align__(16) float smem[48 * 257];   // 49.3 KB, reused across phases
    int bid = blockIdx.x;
    int t = threadIdx.x;
    float* out2 = out + (size_t)NH * NN * NN;

    // ---- phase 1 (297 tasks, one per block; blocks 297..511 idle)
    if (bid < 297)
        task_p1(bid, t, smem, logits, attn_W, attn_b, post_W, post_b, pre_W, pre_b, rank_emb);
    grid_barrier(0);

    // ---- phase 2 (59 tasks)
    if (bid < 59)
        task_p2(bid, t, smem, out2);
    grid_barrier(1);

    // ---- phase 3: block = i-row; wave = 64-j chunk; prefetch all 4 b2 gathers up-front.
    ((uint4*)smem)[t] = ((const uint4*)g_WB)[t];     // sWB: 8 KB (512 x 16B)
    int* sPerm = (int*)(smem + 2048);
    sPerm[t] = g_perm[t];
    float* sAf = smem + 2560;                        // afull: 16 KB
    ((float4*)sAf)[t] = ((const float4*)g_afull)[t];
    ((float4*)sAf)[t + 512] = ((const float4*)g_afull)[t + 512];
    __syncthreads();

    const bf16x8* sWB = (const bf16x8*)smem;         // [8][64]
    int wv = t >> 6, lane = t & 63;
    int g = lane >> 4, r = lane & 15;
    int i = bid;
    bool prm = (i >= ND) && (wv > 0);                // wv>0 => all 4 j-tiles >= ND
    float4 b1 = ((const float4*)boxes)[prm ? sPerm[i] : i];

    // prefetch the 4 b2 rows (independent gathers, in flight under compute)
    float4 b2v[4];
#pragma unroll
    for (int k = 0; k < 4; ++k) {
        int j = wv * 64 + k * 16 + r;
        b2v[k] = ((const float4*)boxes)[prm ? sPerm[j] : j];
    }
    float4 cb4 = *(const float4*)(g_c0 + (g & 1) * 4);
    float4 ai4 = *(const float4*)(sAf + i * NH + (g & 1) * 4);
    const float eps = 1e-5f;

#pragma unroll
    for (int k = 0; k < 4; ++k) {
        float4 b2 = b2v[k];
        int j = wv * 64 + k * 16 + r;
        float ft;
        if (g == 0)      ft = logf(fabsf(b1.x - b2.x) / (b1.z + eps) + 1.0f);
        else if (g == 1) ft = logf(fabsf(b1.y - b2.y) / (b1.w + eps) + 1.0f);
        else if (g == 2) ft = logf((b1.z + eps) / (b2.z + eps));
        else             ft = logf((b1.w + eps) / (b2.w + eps));

        f32x4 acc = {0.f, 0.f, 0.f, 0.f};
#pragma unroll
        for (int s = 0; s < 8; ++s) {
            bf16x8 bfrag;
#pragma unroll
            for (int a = 0; a < 4; ++a) {
                float rev = ft * fa.fr[s * 4 + a];
                rev -= floorf(rev);
                float sv = __builtin_amdgcn_sinf(rev);   // sin(2*pi*rev)
                float cv = __builtin_amdgcn_cosf(rev);
                bfrag[2 * a]     = (short)f2bfbits(sv);
                bfrag[2 * a + 1] = (short)f2bfbits(cv);
            }
            acc = __builtin_amdgcn_mfma_f32_16x16x32_bf16(sWB[s * 64 + lane], bfrag, acc, 0, 0, 0);
        }

        if (g < 2) {
            const float* cbp = (const float*)&cb4;
            const float* aip = (const float*)&ai4;
            const float* aj = sAf + j * NH + g * 4;
#pragma unroll
            for (int qq = 0; qq < 4; ++qq) {
                int h = g * 4 + qq;
                float v = acc[qq] + cbp[qq] + aip[qq] + aj[qq];
                v = v > 0.f ? v : 0.f;
                out[(size_t)h * (NN * NN) + i * NN + j] = v;
            }
        }
    }

    // ---- exit: last block resets barrier flags (state all-zero for next replay)
    __syncthreads();
    if (t == 0) {
        unsigned e = __hip_atomic_fetch_add(&g_exit, 1u, __ATOMIC_ACQ_REL, __HIP_MEMORY_SCOPE_AGENT);
        if (e == NBLK - 1u) {
            __hip_atomic_store(&g_flag[0], 0u, __ATOMIC_RELAXED, __HIP_MEMORY_SCOPE_AGENT);
            __hip_atomic_store(&g_flag[1], 0u, __ATOMIC_RELAXED, __HIP_MEMORY_SCOPE_AGENT);
            __hip_atomic_store(&g_exit, 0u, __ATOMIC_RELEASE, __HIP_MEMORY_SCOPE_AGENT);
        }
    }
}

extern "C" void kernel_launch(void* const* d_in, const int* in_sizes, int n_in,
                              void* d_out, int out_size, void* d_ws, size_t ws_size,
                              hipStream_t stream) {
    const float* boxes    = (const float*)d_in[0];
    const float* logits   = (const float*)d_in[1];
    const float* rank_emb = (const float*)d_in[2];
    const float* pre_W    = (const float*)d_in[3];
    const float* pre_b    = (const float*)d_in[4];
    const float* post_W   = (const float*)d_in[5];
    const float* post_b   = (const float*)d_in[6];
    const float* attn_W   = (const float*)d_in[7];
    const float* attn_b   = (const float*)d_in[8];
    float* out = (float*)d_out;

    FreqArg fa;
    for (int k = 0; k < 32; ++k)
        fa.fr[k] = (float)(100.0 / (2.0 * M_PI) / pow(10000.0, (double)k / 32.0));

    fused_all<<<NBLK, 512, 0, stream>>>(boxes, logits, rank_emb, pre_W, pre_b,
                                        post_W, post_b, attn_W, attn_b, fa, out);
}

// Round 14
// 59.905 us; speedup vs baseline: 2.7711x; 2.7711x over previous
//
#include <hip/hip_runtime.h>
#include <hip/hip_bf16.h>
#include <math.h>

// Sizes fixed by the reference
#define NN 512
#define NQ 448
#define ND 64          // num_denoising
#define NC 91
#define ED 256
#define NH 8

typedef __attribute__((ext_vector_type(8))) short bf16x8;
typedef __attribute__((ext_vector_type(4))) float f32x4;

struct FreqArg { float fr[32]; };

// Device-global scratch (every cell rewritten each launch before read)
__device__ int   g_perm[NN];
__device__ float g_c0[NH];
__device__ float g_u[NH * ED];     // u[h,e] = sum_d w2a[h,d] * pre_W[d,e]
__device__ float g_b2a[NH];        // sum_d w2a[h,d] * pre_b[d]
__device__ __align__(16) unsigned short g_WB[8 * 64 * 8];  // bf16 A-frags [step][lane][elem]

__device__ inline unsigned short f2bfbits(float x) {
    __hip_bfloat16 h = __float2bfloat16(x);
    union { __hip_bfloat16 b; unsigned short u; } cv; cv.b = h; return cv.u;
}

// ---------------- K1: blocks 0..15 = (head h, part): part 0 -> pos-fold -> WB;
// part 1 -> rank-fold -> w2a -> u, b2a. Block 16 = scores+argsort. Block 17 = c0.
__global__ __launch_bounds__(512) void k1(const float* __restrict__ logits,
                                          const float* __restrict__ attn_W,
                                          const float* __restrict__ attn_b,
                                          const float* __restrict__ post_W,
                                          const float* __restrict__ post_b,
                                          const float* __restrict__ pre_W,
                                          const float* __restrict__ pre_b,
                                          float* __restrict__ out2) {
    __shared__ float sAW[ED];
    __shared__ float sHalf[2][ED];   // c-split partial fold
    __shared__ float sW[ED];         // w2a (part 1)
    __shared__ float sU2[2 * ED];    // d-split partial u
    __shared__ float sc[NQ];         // scores (block 16)
    int bid = blockIdx.x, t = threadIdx.x;

    if (bid < 16) {
        int h = bid >> 1, part = bid & 1;   // part 0: cols [0,256) (pos); 1: [256,512) (rank)
        if (t < ED) sAW[t] = attn_W[h * ED + t];
        __syncthreads();
        int dl = t & 255, cp = t >> 8;      // c-half split across the 512 threads
        float m = 0.f;
        const float* pw = post_W + (size_t)(cp * 128) * 512 + part * 256 + dl;
#pragma unroll 16
        for (int ci = 0; ci < 128; ++ci) m = fmaf(sAW[cp * 128 + ci], pw[(size_t)ci * 512], m);
        sHalf[cp][dl] = m;
        __syncthreads();

        if (part == 0) {
            // WB pack for head h (value = pos fold at d = g*64 + 2k + r, k = s*4+(ii>>1))
            if (t < 256) {
                int s = t >> 5, g = (t >> 3) & 3, ii = t & 7;
                int d = g * 64 + ((s * 4 + (ii >> 1)) << 1) + (ii & 1);
                g_WB[s * 512 + (g * 16 + h) * 8 + ii] = f2bfbits(sHalf[0][d] + sHalf[1][d]);
            }
            if (h == 0) {   // zero pad lanes (hh >= 8) deterministically each launch
                for (int v = t; v < 4096; v += 512) {
                    int lane = (v >> 3) & 63;
                    if ((lane & 15) >= NH) g_WB[v] = 0;
                }
            }
        } else {
            if (t < ED) sW[t] = sHalf[0][t] + sHalf[1][t];   // w2a[h, :]
            __syncthreads();
            int e = t & 255, half = t >> 8;
            float acc = 0.f;
            const float* pwc = pre_W + (size_t)(half * 128) * ED + e;
#pragma unroll 16
            for (int d2 = 0; d2 < 128; ++d2) acc = fmaf(sW[half * 128 + d2], pwc[(size_t)d2 * ED], acc);
            sU2[half * 256 + e] = acc;
            __syncthreads();
            if (t < ED) g_u[h * ED + t] = sU2[t] + sU2[256 + t];
            if (t < 64) {
                float v = 0.f;
#pragma unroll
                for (int k = 0; k < 4; ++k) v = fmaf(sW[t + 64 * k], pre_b[t + 64 * k], v);
                for (int off = 32; off > 0; off >>= 1) v += __shfl_down(v, off, 64);
                if (t == 0) g_b2a[h] = v;
            }
        }
    } else if (bid == 16) {
        // scores (coalesced, shfl max-reduce) then stable descending argsort, intra-block
        int W = t >> 6, lane = t & 63;
        for (int qi = 0; qi < 56; ++qi) {
            int q = W * 56 + qi;
            const float* row = logits + (size_t)(ND + q) * NC;
            float m = (lane < NC) ? row[lane] : -INFINITY;
            int c2 = lane + 64;
            if (c2 < NC) m = fmaxf(m, row[c2]);
            for (int off = 32; off > 0; off >>= 1) m = fmaxf(m, __shfl_down(m, off, 64));
            if (lane == 0) sc[q] = m;   // sigmoid(max)==max(sigmoid): rank raw logits
        }
        __syncthreads();
        if (t < NQ) {
            float s1 = sc[t];
            int r1 = 0;
            for (int j = 0; j < NQ; ++j) {
                float sj = sc[j];
                r1 += ((sj > s1) || (sj == s1 && j < t)) ? 1 : 0;
            }
            g_perm[ND + r1] = ND + t;
            out2[ND + r1] = (float)(ND + t);
        }
        if (t < ND) {
            g_perm[t] = t;
            out2[t] = (float)t;
        }
    } else {
        // c0[h] = attn_b[h] + attn_W[h,:] @ post_b  (one wave per head)
        int h = t >> 6, lane = t & 63;
        float v = 0.f;
#pragma unroll
        for (int k = 0; k < 4; ++k) {
            int c = lane + 64 * k;
            v = fmaf(attn_W[h * ED + c], post_b[c], v);
        }
        for (int off = 32; off > 0; off >>= 1) v += __shfl_down(v, off, 64);
        if (lane == 0) g_c0[h] = attn_b[h] + v;
    }
}

// ---------------- K2: main. 1024 blocks x 256 thr; tile = 16 i x 16 j.
// Prologue: afull rows for the tile from remb @ u (redundant, cheap at square tiles).
// Main: R10-proven MFMA formulation, 4 groups per wave.
__global__ __launch_bounds__(256) void mainv2(const float* __restrict__ boxes,
                                              const float* __restrict__ rank_emb,
                                              FreqArg fa,
                                              float* __restrict__ out) {
    __shared__ bf16x8 sWB[8][64];      // 8 KB
    __shared__ float sU[NH][260];      // 8.1 KB, padded
    __shared__ float sAf[32][9];       // afull rows: [0,16): i-rows, [16,32): j-rows
    __shared__ int   sPerm[32];
    __shared__ float sB2a[NH], sC0[NH];
    int t = threadIdx.x, bid = blockIdx.x;
    int i0 = (bid >> 5) * 16, j0 = (bid & 31) * 16;

    ((uint4*)sWB)[t]       = ((const uint4*)g_WB)[t];
    ((uint4*)sWB)[t + 256] = ((const uint4*)g_WB)[t + 256];
    for (int v = t; v < NH * ED; v += 256) sU[v >> 8][v & 255] = g_u[v];
    if (t < NH) { sB2a[t] = g_b2a[t]; sC0[t] = g_c0[t]; }
    if (t < 16) sPerm[t] = g_perm[i0 + t];
    else if (t < 32) sPerm[t] = g_perm[j0 + (t - 16)];
    __syncthreads();

    // afull rows (position-indexed; rows < ND are zero)
    {
        int rr = t >> 3, h = t & 7;    // 32 rows x 8 heads = 256 threads
        int pos = (rr < 16) ? (i0 + rr) : (j0 + (rr - 16));
        float a = 0.f;
        if (pos >= ND) {
            const float* re = rank_emb + (size_t)(pos - ND) * ED;
            for (int e = 0; e < ED; ++e) a = fmaf(re[e], sU[h][e], a);
            a += sB2a[h];
        }
        sAf[rr][h] = a;
    }
    __syncthreads();

    int wv = t >> 6, lane = t & 63;
    int g = lane >> 4, r = lane & 15;
    bool jdn = (j0 < ND);                       // j tile in denoising region (uniform)
    int j = j0 + r;
    float4 b2p = ((const float4*)boxes)[j];     // unpermuted
    float4 b2s = jdn ? b2p : ((const float4*)boxes)[sPerm[16 + r]];
    float4 cb4 = *(const float4*)(sC0 + (g & 1) * 4);
    const float eps = 1e-5f;

#pragma unroll
    for (int gi = 0; gi < 4; ++gi) {
        int iloc = wv * 4 + gi;
        int i = i0 + iloc;
        bool prm = (i >= ND) && !jdn;           // permute ONLY the [64:,64:] block
        float4 b1 = ((const float4*)boxes)[prm ? sPerm[iloc] : i];
        float4 b2 = prm ? b2s : b2p;

        float ft;
        if (g == 0)      ft = logf(fabsf(b1.x - b2.x) / (b1.z + eps) + 1.0f);
        else if (g == 1) ft = logf(fabsf(b1.y - b2.y) / (b1.w + eps) + 1.0f);
        else if (g == 2) ft = logf((b1.z + eps) / (b2.z + eps));
        else             ft = logf((b1.w + eps) / (b2.w + eps));

        f32x4 acc = {0.f, 0.f, 0.f, 0.f};
#pragma unroll
        for (int s = 0; s < 8; ++s) {
            bf16x8 bfrag;
#pragma unroll
            for (int a = 0; a < 4; ++a) {
                float rev = ft * fa.fr[s * 4 + a];
                rev -= floorf(rev);
                float sv = __builtin_amdgcn_sinf(rev);   // sin(2*pi*rev)
                float cv = __builtin_amdgcn_cosf(rev);
                bfrag[2 * a]     = (short)f2bfbits(sv);
                bfrag[2 * a + 1] = (short)f2bfbits(cv);
            }
            acc = __builtin_amdgcn_mfma_f32_16x16x32_bf16(sWB[s][lane], bfrag, acc, 0, 0, 0);
        }

        // D: row = g*4 + qq (head, valid < 8 -> g < 2), col = r (pair)
        if (g < 2) {
            const float* cbp = (const float*)&cb4;
#pragma unroll
            for (int qq = 0; qq < 4; ++qq) {
                int h = g * 4 + qq;
                float v = acc[qq] + cbp[qq] + sAf[iloc][h] + sAf[16 + r][h];
                v = v > 0.f ? v : 0.f;
                out[(size_t)h * (NN * NN) + (size_t)i * NN + j] = v;
            }
        }
    }
}

extern "C" void kernel_launch(void* const* d_in, const int* in_sizes, int n_in,
                              void* d_out, int out_size, void* d_ws, size_t ws_size,
                              hipStream_t stream) {
    const float* boxes    = (const float*)d_in[0];
    const float* logits   = (const float*)d_in[1];
    const float* rank_emb = (const float*)d_in[2];
    const float* pre_W    = (const float*)d_in[3];
    const float* pre_b    = (const float*)d_in[4];
    const float* post_W   = (const float*)d_in[5];
    const float* post_b   = (const float*)d_in[6];
    const float* attn_W   = (const float*)d_in[7];
    const float* attn_b   = (const float*)d_in[8];
    float* out = (float*)d_out;

    k1<<<18, 512, 0, stream>>>(logits, attn_W, attn_b, post_W, post_b,
                               pre_W, pre_b, out + (size_t)NH * NN * NN);

    FreqArg fa;
    for (int k = 0; k < 32; ++k)
        fa.fr[k] = (float)(100.0 / (2.0 * M_PI) / pow(10000.0, (double)k / 32.0));

    mainv2<<<1024, 256, 0, stream>>>(boxes, rank_emb, fa, out);
}